// Round 4
// baseline (465.505 us; speedup 1.0000x reference)
//
#include <hip/hip_runtime.h>

#define D 128
#define NSLICE 8     // = number of XCDs
#define SW 16        // slice width = D / NSLICE; 16 floats = 64B; 3.2MB slice fits 4MB L2
#define GNODES 16    // nodes per gather block (256 threads / 16-lane groups)
#define NB 32        // nodes per gemm block

// ---------------- CSR build: histogram ----------------
__global__ __launch_bounds__(256) void hist_kernel(
    const int* __restrict__ dst, int* __restrict__ hist, int n_edges)
{
    int i = blockIdx.x * 256 + threadIdx.x;
    if (i < n_edges) atomicAdd(&hist[dst[i]], 1);
}

// ---------------- CSR build: exclusive scan (single block, 1024 thr) -------
__global__ __launch_bounds__(1024) void scan_kernel(
    const int* __restrict__ hist, int* __restrict__ row_start,
    int* __restrict__ cursor, int n)
{
    __shared__ int wsum[16];
    const int tid = threadIdx.x, lane = tid & 63, w = tid >> 6;
    int running = 0;
    const int nchunk = (n + 4095) >> 12;
    for (int c = 0; c < nchunk; ++c) {
        const int base = c * 4096 + tid * 4;
        int v0 = (base + 0 < n) ? hist[base + 0] : 0;
        int v1 = (base + 1 < n) ? hist[base + 1] : 0;
        int v2 = (base + 2 < n) ? hist[base + 2] : 0;
        int v3 = (base + 3 < n) ? hist[base + 3] : 0;
        const int s1 = v0 + v1, s2 = s1 + v2, s3 = s2 + v3;
        int incl = s3;
        #pragma unroll
        for (int off = 1; off < 64; off <<= 1) {
            int t = __shfl_up(incl, off, 64);
            if (lane >= off) incl += t;
        }
        if (lane == 63) wsum[w] = incl;
        __syncthreads();
        int wp = 0, ct = 0;
        #pragma unroll
        for (int k = 0; k < 16; ++k) { int s = wsum[k]; if (k < w) wp += s; ct += s; }
        const int ex = running + wp + incl - s3;
        if (base + 0 < n) { row_start[base + 0] = ex;      cursor[base + 0] = ex; }
        if (base + 1 < n) { row_start[base + 1] = ex + v0; cursor[base + 1] = ex + v0; }
        if (base + 2 < n) { row_start[base + 2] = ex + s1; cursor[base + 2] = ex + s1; }
        if (base + 3 < n) { row_start[base + 3] = ex + s2; cursor[base + 3] = ex + s2; }
        running += ct;
        __syncthreads();
    }
    if (tid == 0) row_start[n] = running;
}

// ---------------- CSR build: bucket fill ----------------
__global__ __launch_bounds__(256) void fill_kernel(
    const int* __restrict__ src, const int* __restrict__ dst,
    int* __restrict__ cursor, int* __restrict__ adj, int n_edges)
{
    int i = blockIdx.x * 256 + threadIdx.x;
    if (i < n_edges) {
        const int d = dst[i];
        const int pos = atomicAdd(&cursor[d], 1);
        adj[pos] = src[i];
    }
}

// ------- XCD-affine column-sliced gather: msg[n][c] = mean_{s in adj(n)} h[s][c]
// slice = blockIdx & 7 == XCD id (HW round-robins blockIdx across 8 XCDs),
// so each XCD's L2 only ever sees a 3.2MB column slice of h -> gathers L2-hit.
__global__ __launch_bounds__(256) void gather_kernel(
    const float* __restrict__ hin, const int* __restrict__ adj,
    const int* __restrict__ row_start, float* __restrict__ msg, int n_nodes)
{
    const int slice = blockIdx.x & (NSLICE - 1);
    const int nb    = blockIdx.x >> 3;
    const int g     = threadIdx.x >> 4;     // 16-lane group -> one node
    const int l     = threadIdx.x & 15;
    const int node  = nb * GNODES + g;
    if (node >= n_nodes) return;
    const int col = slice * SW + l;

    const int s0 = row_start[node], s1 = row_start[node + 1];
    float a0 = 0.f, a1 = 0.f, a2 = 0.f, a3 = 0.f;
    int p = s0;
    for (; p + 3 < s1; p += 4) {            // 4 independent 64B row-slice loads
        const int ia = adj[p], ib = adj[p + 1], ic = adj[p + 2], id = adj[p + 3];
        a0 += hin[(size_t)ia * D + col];
        a1 += hin[(size_t)ib * D + col];
        a2 += hin[(size_t)ic * D + col];
        a3 += hin[(size_t)id * D + col];
    }
    for (; p < s1; ++p) a0 += hin[(size_t)adj[p] * D + col];

    const int dg = s1 - s0;
    const float inv = 1.0f / (float)(dg > 0 ? dg : 1);
    msg[(size_t)node * D + col] = ((a0 + a1) + (a2 + a3)) * inv;
}

// -------- gemm: out = relu([h, msg] @ W + b) ----------------
__global__ __launch_bounds__(256) void gemm_kernel(
    const float* __restrict__ hin, const float* __restrict__ msg,
    const float* __restrict__ W, const float* __restrict__ bias,
    float* __restrict__ out, int n_nodes)
{
    __shared__ float hc[NB][2 * D];   // 32 KB
    const int tid  = threadIdx.x;
    const int base = blockIdx.x * NB;

    // stage [h | msg] rows: 8 x coalesced float4 sweeps
    #pragma unroll
    for (int i = 0; i < 8; ++i) {
        const int flat = i * 1024 + tid * 4;   // element of [NB][256]
        const int n = flat >> 8;
        const int c = flat & 255;
        const int node = base + n;
        float4 v = make_float4(0.f, 0.f, 0.f, 0.f);
        if (node < n_nodes) {
            const float* srcp = (c < D) ? (hin + (size_t)node * D + c)
                                        : (msg + (size_t)node * D + (c - D));
            v = *reinterpret_cast<const float4*>(srcp);
        }
        *reinterpret_cast<float4*>(&hc[n][c]) = v;
    }
    __syncthreads();

    const int j = tid & 127;          // output column
    const int g = tid >> 7;           // node-half
    float acc[16];
    const float bj = bias[j];
    #pragma unroll
    for (int n = 0; n < 16; ++n) acc[n] = bj;

    for (int k = 0; k < 2 * D; k += 4) {
        const float w0 = W[(k + 0) * D + j];
        const float w1 = W[(k + 1) * D + j];
        const float w2 = W[(k + 2) * D + j];
        const float w3 = W[(k + 3) * D + j];
        #pragma unroll
        for (int n = 0; n < 16; ++n) {
            const float4 x = *reinterpret_cast<const float4*>(&hc[g * 16 + n][k]);
            acc[n] = fmaf(x.x, w0, fmaf(x.y, w1, fmaf(x.z, w2, fmaf(x.w, w3, acc[n]))));
        }
    }

    #pragma unroll
    for (int n = 0; n < 16; ++n) {
        const int node = base + g * 16 + n;
        if (node < n_nodes)
            out[(size_t)node * D + j] = fmaxf(acc[n], 0.f);
    }
}

// ---------------------------------------------------------------------------
extern "C" void kernel_launch(void* const* d_in, const int* in_sizes, int n_in,
                              void* d_out, int out_size, void* d_ws, size_t ws_size,
                              hipStream_t stream)
{
    const float* h    = (const float*)d_in[0];
    const int*   esrc = (const int*)  d_in[1];
    const int*   edst = (const int*)  d_in[2];
    const float* W1   = (const float*)d_in[3];
    const float* b1   = (const float*)d_in[4];
    const float* W2   = (const float*)d_in[5];
    const float* b2   = (const float*)d_in[6];
    float* out = (float*)d_out;

    const int n_nodes = in_sizes[0] / D;
    const int n_edges = in_sizes[1];

    // workspace layout
    float* h1        = (float*)d_ws;                       // [N][D]
    float* msg       = h1 + (size_t)n_nodes * D;           // [N][D]
    int*   adj       = (int*)(msg + (size_t)n_nodes * D);  // [E]
    int*   hist      = adj + n_edges;                      // [N]
    int*   row_start = hist + n_nodes;                     // [N+1]
    int*   cursor    = row_start + n_nodes + 1;            // [N]

    const int eblocks = (n_edges + 255) / 256;
    const int nbg     = (n_nodes + GNODES - 1) / GNODES;   // gather node-blocks
    const int gather_blocks = nbg * NSLICE;
    const int gemm_blocks   = (n_nodes + NB - 1) / NB;

    // ---- CSR build (once; shared by both layers) ----
    hipMemsetAsync(hist, 0, (size_t)n_nodes * sizeof(int), stream);
    hist_kernel<<<eblocks, 256, 0, stream>>>(edst, hist, n_edges);
    scan_kernel<<<1, 1024, 0, stream>>>(hist, row_start, cursor, n_nodes);
    fill_kernel<<<eblocks, 256, 0, stream>>>(esrc, edst, cursor, adj, n_edges);

    // ---- layer 1: h -> h1 ----
    gather_kernel<<<gather_blocks, 256, 0, stream>>>(h, adj, row_start, msg, n_nodes);
    gemm_kernel  <<<gemm_blocks,   256, 0, stream>>>(h, msg, W1, b1, h1, n_nodes);

    // ---- layer 2: h1 -> out ----
    gather_kernel<<<gather_blocks, 256, 0, stream>>>(h1, adj, row_start, msg, n_nodes);
    gemm_kernel  <<<gemm_blocks,   256, 0, stream>>>(h1, msg, W2, b2, out, n_nodes);
}

// Round 5
// 423.573 us; speedup vs baseline: 1.0990x; 1.0990x over previous
//
#include <hip/hip_runtime.h>

#define D 128
#define NB 32        // nodes per gemm block
#define SORT_CAP 64  // rows longer than this are left unsorted (perf-only opt)

// ---------------- CSR build: histogram ----------------
__global__ __launch_bounds__(256) void hist_kernel(
    const int* __restrict__ dst, int* __restrict__ hist, int n_edges)
{
    int i = blockIdx.x * 256 + threadIdx.x;
    if (i < n_edges) atomicAdd(&hist[dst[i]], 1);
}

// ---------------- CSR build: exclusive scan (single block, 1024 thr) -------
__global__ __launch_bounds__(1024) void scan_kernel(
    const int* __restrict__ hist, int* __restrict__ row_start,
    int* __restrict__ cursor, int n)
{
    __shared__ int wsum[16];
    const int tid = threadIdx.x, lane = tid & 63, w = tid >> 6;
    int running = 0;
    const int nchunk = (n + 4095) >> 12;
    for (int c = 0; c < nchunk; ++c) {
        const int base = c * 4096 + tid * 4;
        int v0 = (base + 0 < n) ? hist[base + 0] : 0;
        int v1 = (base + 1 < n) ? hist[base + 1] : 0;
        int v2 = (base + 2 < n) ? hist[base + 2] : 0;
        int v3 = (base + 3 < n) ? hist[base + 3] : 0;
        const int s1 = v0 + v1, s2 = s1 + v2, s3 = s2 + v3;
        int incl = s3;
        #pragma unroll
        for (int off = 1; off < 64; off <<= 1) {
            int t = __shfl_up(incl, off, 64);
            if (lane >= off) incl += t;
        }
        if (lane == 63) wsum[w] = incl;
        __syncthreads();
        int wp = 0, ct = 0;
        #pragma unroll
        for (int k = 0; k < 16; ++k) { int s = wsum[k]; if (k < w) wp += s; ct += s; }
        const int ex = running + wp + incl - s3;
        if (base + 0 < n) { row_start[base + 0] = ex;      cursor[base + 0] = ex; }
        if (base + 1 < n) { row_start[base + 1] = ex + v0; cursor[base + 1] = ex + v0; }
        if (base + 2 < n) { row_start[base + 2] = ex + s1; cursor[base + 2] = ex + s1; }
        if (base + 3 < n) { row_start[base + 3] = ex + s2; cursor[base + 3] = ex + s2; }
        running += ct;
        __syncthreads();
    }
    if (tid == 0) row_start[n] = running;
}

// ---------------- CSR build: bucket fill ----------------
__global__ __launch_bounds__(256) void fill_kernel(
    const int* __restrict__ src, const int* __restrict__ dst,
    int* __restrict__ cursor, int* __restrict__ adj, int n_edges)
{
    int i = blockIdx.x * 256 + threadIdx.x;
    if (i < n_edges) {
        const int d = dst[i];
        const int pos = atomicAdd(&cursor[d], 1);
        adj[pos] = src[i];
    }
}

// ------- per-row insertion sort (ascending src) in LDS --------------------
// Purpose: all concurrent gather waves then sweep src 0->N in lockstep, so the
// active src window stays small and L2/LLC-resident. Perf-only: skipping long
// rows is harmless for correctness.
__global__ __launch_bounds__(128) void sort_rows(
    int* __restrict__ adj, const int* __restrict__ row_start, int n_nodes)
{
    __shared__ int buf[128 * 68];           // 68-int stride: spreads banks
    const int tid = threadIdx.x;
    const int row = blockIdx.x * 128 + tid;
    if (row >= n_nodes) return;
    const int s0 = row_start[row], s1 = row_start[row + 1];
    const int d = s1 - s0;
    if (d <= 1 || d > SORT_CAP) return;
    int* b = &buf[tid * 68];
    for (int i = 0; i < d; ++i) b[i] = adj[s0 + i];
    for (int i = 1; i < d; ++i) {
        const int key = b[i];
        int q = i - 1;
        while (q >= 0 && b[q] > key) { b[q + 1] = b[q]; --q; }
        b[q + 1] = key;
    }
    for (int i = 0; i < d; ++i) adj[s0 + i] = b[i];
}

// ------- gather: one 64-lane wave per dst node; full 512B rows (float2/lane)
__global__ __launch_bounds__(256) void gather_kernel(
    const float* __restrict__ hin, const int* __restrict__ adj,
    const int* __restrict__ row_start, float* __restrict__ msg, int n_nodes)
{
    const int lane = threadIdx.x & 63;
    const int node = (blockIdx.x * 256 + threadIdx.x) >> 6;
    if (node >= n_nodes) return;
    const float2* h2 = reinterpret_cast<const float2*>(hin);

    const int s0 = row_start[node], s1 = row_start[node + 1];
    float ax0 = 0.f, ay0 = 0.f, ax1 = 0.f, ay1 = 0.f;
    float ax2 = 0.f, ay2 = 0.f, ax3 = 0.f, ay3 = 0.f;
    int p = s0;
    for (; p + 3 < s1; p += 4) {            // 4 independent 512B row loads
        const int ia = adj[p], ib = adj[p + 1], ic = adj[p + 2], id = adj[p + 3];
        const float2 a = h2[(size_t)ia * 64 + lane];
        const float2 b = h2[(size_t)ib * 64 + lane];
        const float2 c = h2[(size_t)ic * 64 + lane];
        const float2 e = h2[(size_t)id * 64 + lane];
        ax0 += a.x; ay0 += a.y; ax1 += b.x; ay1 += b.y;
        ax2 += c.x; ay2 += c.y; ax3 += e.x; ay3 += e.y;
    }
    for (; p < s1; ++p) {
        const float2 a = h2[(size_t)adj[p] * 64 + lane];
        ax0 += a.x; ay0 += a.y;
    }
    const int dg = s1 - s0;
    const float inv = 1.0f / (float)(dg > 0 ? dg : 1);
    float2 r;
    r.x = ((ax0 + ax1) + (ax2 + ax3)) * inv;
    r.y = ((ay0 + ay1) + (ay2 + ay3)) * inv;
    reinterpret_cast<float2*>(msg)[(size_t)node * 64 + lane] = r;
}

// -------- gemm: out = relu([h, msg] @ W + b), 4 cols x 4 nodes per thread --
__global__ __launch_bounds__(256) void gemm_kernel(
    const float* __restrict__ hin, const float* __restrict__ msg,
    const float* __restrict__ W, const float* __restrict__ bias,
    float* __restrict__ out, int n_nodes)
{
    __shared__ float hc[NB][2 * D];   // 32 KB
    const int tid  = threadIdx.x;
    const int base = blockIdx.x * NB;

    // stage [h | msg] rows: 8 x coalesced float4 sweeps
    #pragma unroll
    for (int i = 0; i < 8; ++i) {
        const int flat = i * 1024 + tid * 4;   // element of [NB][256]
        const int n = flat >> 8;
        const int c = flat & 255;
        const int node = base + n;
        float4 v = make_float4(0.f, 0.f, 0.f, 0.f);
        if (node < n_nodes) {
            const float* srcp = (c < D) ? (hin + (size_t)node * D + c)
                                        : (msg + (size_t)node * D + (c - D));
            v = *reinterpret_cast<const float4*>(srcp);
        }
        *reinterpret_cast<float4*>(&hc[n][c]) = v;
    }
    __syncthreads();

    const int cg = tid & 31;          // col group: cols cg*4 .. cg*4+3
    const int ng = tid >> 5;          // node group: nodes ng*4 .. ng*4+3
    const int c0 = cg * 4;
    const int n0 = ng * 4;

    float acc[4][4];
    const float4 bv = *reinterpret_cast<const float4*>(&bias[c0]);
    #pragma unroll
    for (int ni = 0; ni < 4; ++ni) {
        acc[ni][0] = bv.x; acc[ni][1] = bv.y; acc[ni][2] = bv.z; acc[ni][3] = bv.w;
    }

    for (int k = 0; k < 2 * D; k += 4) {
        float4 w0 = *reinterpret_cast<const float4*>(&W[(k + 0) * D + c0]);
        float4 w1 = *reinterpret_cast<const float4*>(&W[(k + 1) * D + c0]);
        float4 w2 = *reinterpret_cast<const float4*>(&W[(k + 2) * D + c0]);
        float4 w3 = *reinterpret_cast<const float4*>(&W[(k + 3) * D + c0]);
        #pragma unroll
        for (int ni = 0; ni < 4; ++ni) {
            const float4 x = *reinterpret_cast<const float4*>(&hc[n0 + ni][k]);
            acc[ni][0] = fmaf(x.x, w0.x, fmaf(x.y, w1.x, fmaf(x.z, w2.x, fmaf(x.w, w3.x, acc[ni][0]))));
            acc[ni][1] = fmaf(x.x, w0.y, fmaf(x.y, w1.y, fmaf(x.z, w2.y, fmaf(x.w, w3.y, acc[ni][1]))));
            acc[ni][2] = fmaf(x.x, w0.z, fmaf(x.y, w1.z, fmaf(x.z, w2.z, fmaf(x.w, w3.z, acc[ni][2]))));
            acc[ni][3] = fmaf(x.x, w0.w, fmaf(x.y, w1.w, fmaf(x.z, w2.w, fmaf(x.w, w3.w, acc[ni][3]))));
        }
    }

    #pragma unroll
    for (int ni = 0; ni < 4; ++ni) {
        const int node = base + n0 + ni;
        if (node < n_nodes) {
            float4 r;
            r.x = fmaxf(acc[ni][0], 0.f);
            r.y = fmaxf(acc[ni][1], 0.f);
            r.z = fmaxf(acc[ni][2], 0.f);
            r.w = fmaxf(acc[ni][3], 0.f);
            *reinterpret_cast<float4*>(&out[(size_t)node * D + c0]) = r;
        }
    }
}

// ---------------------------------------------------------------------------
extern "C" void kernel_launch(void* const* d_in, const int* in_sizes, int n_in,
                              void* d_out, int out_size, void* d_ws, size_t ws_size,
                              hipStream_t stream)
{
    const float* h    = (const float*)d_in[0];
    const int*   esrc = (const int*)  d_in[1];
    const int*   edst = (const int*)  d_in[2];
    const float* W1   = (const float*)d_in[3];
    const float* b1   = (const float*)d_in[4];
    const float* W2   = (const float*)d_in[5];
    const float* b2   = (const float*)d_in[6];
    float* out = (float*)d_out;

    const int n_nodes = in_sizes[0] / D;
    const int n_edges = in_sizes[1];

    // workspace layout
    float* h1        = (float*)d_ws;                       // [N][D]
    float* msg       = h1 + (size_t)n_nodes * D;           // [N][D]
    int*   adj       = (int*)(msg + (size_t)n_nodes * D);  // [E]
    int*   hist      = adj + n_edges;                      // [N]
    int*   row_start = hist + n_nodes;                     // [N+1]
    int*   cursor    = row_start + n_nodes + 1;            // [N]

    const int eblocks = (n_edges + 255) / 256;
    const int gather_blocks = (n_nodes + 3) / 4;           // 1 wave per node
    const int gemm_blocks   = (n_nodes + NB - 1) / NB;
    const int sort_blocks   = (n_nodes + 127) / 128;

    // ---- CSR build (once; shared by both layers) ----
    hipMemsetAsync(hist, 0, (size_t)n_nodes * sizeof(int), stream);
    hist_kernel<<<eblocks, 256, 0, stream>>>(edst, hist, n_edges);
    scan_kernel<<<1, 1024, 0, stream>>>(hist, row_start, cursor, n_nodes);
    fill_kernel<<<eblocks, 256, 0, stream>>>(esrc, edst, cursor, adj, n_edges);
    sort_rows<<<sort_blocks, 128, 0, stream>>>(adj, row_start, n_nodes);

    // ---- layer 1: h -> h1 ----
    gather_kernel<<<gather_blocks, 256, 0, stream>>>(h, adj, row_start, msg, n_nodes);
    gemm_kernel  <<<gemm_blocks,   256, 0, stream>>>(h, msg, W1, b1, h1, n_nodes);

    // ---- layer 2: h1 -> out ----
    gather_kernel<<<gather_blocks, 256, 0, stream>>>(h1, adj, row_start, msg, n_nodes);
    gemm_kernel  <<<gemm_blocks,   256, 0, stream>>>(h1, msg, W2, b2, out, n_nodes);
}

// Round 6
// 340.686 us; speedup vs baseline: 1.3664x; 1.2433x over previous
//
#include <hip/hip_runtime.h>

#define D 128
#define SORT_CAP 64

typedef short short8 __attribute__((ext_vector_type(8)));
typedef float f32x4  __attribute__((ext_vector_type(4)));

__device__ __forceinline__ unsigned short f2bf(float f) {
    unsigned int u = __builtin_bit_cast(unsigned int, f);
    u += 0x7FFFu + ((u >> 16) & 1u);           // round-to-nearest-even
    return (unsigned short)(u >> 16);
}

// ---------------- CSR build: histogram ----------------
__global__ __launch_bounds__(256) void hist_kernel(
    const int* __restrict__ dst, int* __restrict__ hist, int n_edges)
{
    int i = blockIdx.x * 256 + threadIdx.x;
    if (i < n_edges) atomicAdd(&hist[dst[i]], 1);
}

// ---------------- CSR build: exclusive scan (single block, 1024 thr) -------
__global__ __launch_bounds__(1024) void scan_kernel(
    const int* __restrict__ hist, int* __restrict__ row_start,
    int* __restrict__ cursor, int n)
{
    __shared__ int wsum[16];
    const int tid = threadIdx.x, lane = tid & 63, w = tid >> 6;
    int running = 0;
    const int nchunk = (n + 4095) >> 12;
    for (int c = 0; c < nchunk; ++c) {
        const int base = c * 4096 + tid * 4;
        int v0 = (base + 0 < n) ? hist[base + 0] : 0;
        int v1 = (base + 1 < n) ? hist[base + 1] : 0;
        int v2 = (base + 2 < n) ? hist[base + 2] : 0;
        int v3 = (base + 3 < n) ? hist[base + 3] : 0;
        const int s1 = v0 + v1, s2 = s1 + v2, s3 = s2 + v3;
        int incl = s3;
        #pragma unroll
        for (int off = 1; off < 64; off <<= 1) {
            int t = __shfl_up(incl, off, 64);
            if (lane >= off) incl += t;
        }
        if (lane == 63) wsum[w] = incl;
        __syncthreads();
        int wp = 0, ct = 0;
        #pragma unroll
        for (int k = 0; k < 16; ++k) { int s = wsum[k]; if (k < w) wp += s; ct += s; }
        const int ex = running + wp + incl - s3;
        if (base + 0 < n) { row_start[base + 0] = ex;      cursor[base + 0] = ex; }
        if (base + 1 < n) { row_start[base + 1] = ex + v0; cursor[base + 1] = ex + v0; }
        if (base + 2 < n) { row_start[base + 2] = ex + s1; cursor[base + 2] = ex + s1; }
        if (base + 3 < n) { row_start[base + 3] = ex + s2; cursor[base + 3] = ex + s2; }
        running += ct;
        __syncthreads();
    }
    if (tid == 0) row_start[n] = running;
}

// ---------------- CSR build: bucket fill ----------------
__global__ __launch_bounds__(256) void fill_kernel(
    const int* __restrict__ src, const int* __restrict__ dst,
    int* __restrict__ cursor, int* __restrict__ adj, int n_edges)
{
    int i = blockIdx.x * 256 + threadIdx.x;
    if (i < n_edges) {
        const int d = dst[i];
        const int pos = atomicAdd(&cursor[d], 1);
        adj[pos] = src[i];
    }
}

// ------- per-row insertion sort (ascending src): lockstep L2-window sweep --
__global__ __launch_bounds__(128) void sort_rows(
    int* __restrict__ adj, const int* __restrict__ row_start, int n_nodes)
{
    __shared__ int buf[128 * 68];
    const int tid = threadIdx.x;
    const int row = blockIdx.x * 128 + tid;
    if (row >= n_nodes) return;
    const int s0 = row_start[row], s1 = row_start[row + 1];
    const int d = s1 - s0;
    if (d <= 1 || d > SORT_CAP) return;
    int* b = &buf[tid * 68];
    for (int i = 0; i < d; ++i) b[i] = adj[s0 + i];
    for (int i = 1; i < d; ++i) {
        const int key = b[i];
        int q = i - 1;
        while (q >= 0 && b[q] > key) { b[q + 1] = b[q]; --q; }
        b[q + 1] = key;
    }
    for (int i = 0; i < d; ++i) adj[s0 + i] = b[i];
}

// ------- gather: one 64-lane wave per dst node; full 512B rows -------------
__global__ __launch_bounds__(256) void gather_kernel(
    const float* __restrict__ hin, const int* __restrict__ adj,
    const int* __restrict__ row_start, float* __restrict__ msg, int n_nodes)
{
    const int lane = threadIdx.x & 63;
    const int node = (blockIdx.x * 256 + threadIdx.x) >> 6;
    if (node >= n_nodes) return;
    const float2* h2 = reinterpret_cast<const float2*>(hin);

    const int s0 = row_start[node], s1 = row_start[node + 1];
    float ax0 = 0.f, ay0 = 0.f, ax1 = 0.f, ay1 = 0.f;
    float ax2 = 0.f, ay2 = 0.f, ax3 = 0.f, ay3 = 0.f;
    int p = s0;
    for (; p + 3 < s1; p += 4) {
        const int ia = adj[p], ib = adj[p + 1], ic = adj[p + 2], id = adj[p + 3];
        const float2 a = h2[(size_t)ia * 64 + lane];
        const float2 b = h2[(size_t)ib * 64 + lane];
        const float2 c = h2[(size_t)ic * 64 + lane];
        const float2 e = h2[(size_t)id * 64 + lane];
        ax0 += a.x; ay0 += a.y; ax1 += b.x; ay1 += b.y;
        ax2 += c.x; ay2 += c.y; ax3 += e.x; ay3 += e.y;
    }
    for (; p < s1; ++p) {
        const float2 a = h2[(size_t)adj[p] * 64 + lane];
        ax0 += a.x; ay0 += a.y;
    }
    const int dg = s1 - s0;
    const float inv = 1.0f / (float)(dg > 0 ? dg : 1);
    float2 r;
    r.x = ((ax0 + ax1) + (ax2 + ax3)) * inv;
    r.y = ((ay0 + ay1) + (ay2 + ay3)) * inv;
    reinterpret_cast<float2*>(msg)[(size_t)node * 64 + lane] = r;
}

// ------- W -> fragment-major bf16 for mfma_f32_16x16x32_bf16 ---------------
// Wfrag[((ct*8+kc)*64 + lane)*8 + j] = bf16( W[kc*32+(lane>>4)*8+j][ct*16+(lane&15)] )
__global__ __launch_bounds__(256) void wconv_kernel(
    const float* __restrict__ W1, const float* __restrict__ W2,
    unsigned short* __restrict__ wf1, unsigned short* __restrict__ wf2)
{
    const int t = blockIdx.x * 256 + threadIdx.x;   // 0..8191
    const int which = t >> 12;                      // 0: W1, 1: W2
    const int u = t & 4095;                         // (frag, lane)
    const float* W = which ? W2 : W1;
    unsigned short* wf = which ? wf2 : wf1;
    const int lane = u & 63;
    const int frag = u >> 6;                        // ct*8 + kc
    const int ctb  = frag >> 3;
    const int kc   = frag & 7;
    const int col  = ctb * 16 + (lane & 15);
    const int k0   = kc * 32 + (lane >> 4) * 8;
    unsigned short o[8];
    #pragma unroll
    for (int j = 0; j < 8; ++j) o[j] = f2bf(W[(size_t)(k0 + j) * D + col]);
    #pragma unroll
    for (int j = 0; j < 8; ++j) wf[(size_t)u * 8 + j] = o[j];
}

// -------- MFMA gemm: out = relu([h,msg]_bf16 @ Wfrag + b) ------------------
// Block: 256 thr = 4 waves, 64 nodes. Wave: 16 nodes x 128 cols = 8 ct-tiles,
// K=256 in 8 kc-chunks of 32. A staged bf16 in LDS (XOR-swizzled chunks).
__global__ __launch_bounds__(256) void gemm_mfma(
    const float* __restrict__ hin, const float* __restrict__ msg,
    const unsigned short* __restrict__ wfrag, const float* __restrict__ bias,
    float* __restrict__ out, int n_nodes)
{
    __shared__ unsigned short sA[64 * 256];   // 32 KB: 64 rows x 256 bf16
    const int tid  = threadIdx.x;
    const int base = blockIdx.x * 64;

    // ---- stage [h | msg] rows as bf16, 16B chunks, swizzle cc^=(r&7) ----
    #pragma unroll
    for (int it = 0; it < 8; ++it) {
        const int f  = it * 256 + tid;        // chunk id 0..2047
        const int r  = f >> 5;                // row 0..63
        const int cc = f & 31;                // 16B chunk (8 bf16)
        const int node = base + r;
        float4 v0 = make_float4(0.f,0.f,0.f,0.f), v1 = v0;
        if (node < n_nodes) {
            const float* sp = (cc < 16) ? hin + (size_t)node * D + cc * 8
                                        : msg + (size_t)node * D + (cc - 16) * 8;
            v0 = *reinterpret_cast<const float4*>(sp);
            v1 = *reinterpret_cast<const float4*>(sp + 4);
        }
        union { short8 s; unsigned short u[8]; } pk;
        pk.u[0]=f2bf(v0.x); pk.u[1]=f2bf(v0.y); pk.u[2]=f2bf(v0.z); pk.u[3]=f2bf(v0.w);
        pk.u[4]=f2bf(v1.x); pk.u[5]=f2bf(v1.y); pk.u[6]=f2bf(v1.z); pk.u[7]=f2bf(v1.w);
        *reinterpret_cast<short8*>(&sA[r * 256 + ((cc ^ (r & 7)) * 8)]) = pk.s;
    }
    __syncthreads();

    const int wv   = tid >> 6;       // wave 0..3 -> nodes wv*16..wv*16+15
    const int lane = tid & 63;
    const int lrow = wv * 16 + (lane & 15);       // LDS row for A frags
    const int lgrp = lane >> 4;                   // k-subgroup 0..3

    // ---- load 8 A fragments (one per kc) from LDS ----
    short8 a[8];
    #pragma unroll
    for (int kc = 0; kc < 8; ++kc) {
        const int chunk = kc * 4 + lgrp;
        a[kc] = *reinterpret_cast<const short8*>(
            &sA[lrow * 256 + ((chunk ^ (lrow & 7)) * 8)]);
    }

    // ---- MFMA over 8 col-tiles ----
    const short8* wf = reinterpret_cast<const short8*>(wfrag);
    f32x4 acc[8];
    #pragma unroll
    for (int ct = 0; ct < 8; ++ct) {
        const float bb = bias[ct * 16 + (lane & 15)];
        acc[ct] = (f32x4){bb, bb, bb, bb};
    }
    #pragma unroll
    for (int ct = 0; ct < 8; ++ct) {
        #pragma unroll
        for (int kc = 0; kc < 8; ++kc) {
            const short8 b = wf[(ct * 8 + kc) * 64 + lane];
            acc[ct] = __builtin_amdgcn_mfma_f32_16x16x32_bf16(a[kc], b, acc[ct], 0, 0, 0);
        }
    }

    // ---- ReLU + store: node = base+wv*16+(lane>>4)*4+reg, col = ct*16+(lane&15)
    #pragma unroll
    for (int ct = 0; ct < 8; ++ct) {
        const int col = ct * 16 + (lane & 15);
        #pragma unroll
        for (int rg = 0; rg < 4; ++rg) {
            const int node = base + wv * 16 + lgrp * 4 + rg;
            if (node < n_nodes)
                out[(size_t)node * D + col] = fmaxf(acc[ct][rg], 0.f);
        }
    }
}

// ---------------------------------------------------------------------------
extern "C" void kernel_launch(void* const* d_in, const int* in_sizes, int n_in,
                              void* d_out, int out_size, void* d_ws, size_t ws_size,
                              hipStream_t stream)
{
    const float* h    = (const float*)d_in[0];
    const int*   esrc = (const int*)  d_in[1];
    const int*   edst = (const int*)  d_in[2];
    const float* W1   = (const float*)d_in[3];
    const float* b1   = (const float*)d_in[4];
    const float* W2   = (const float*)d_in[5];
    const float* b2   = (const float*)d_in[6];
    float* out = (float*)d_out;

    const int n_nodes = in_sizes[0] / D;
    const int n_edges = in_sizes[1];

    // workspace layout
    float* h1        = (float*)d_ws;                       // [N][D]
    float* msg       = h1 + (size_t)n_nodes * D;           // [N][D]
    int*   adj       = (int*)(msg + (size_t)n_nodes * D);  // [E]
    int*   hist      = adj + n_edges;                      // [N]
    int*   row_start = hist + n_nodes;                     // [N+1]
    int*   cursor    = row_start + n_nodes + 1;            // [N]
    size_t woff = (size_t)(cursor + n_nodes) - (size_t)d_ws;
    woff = (woff + 15) & ~(size_t)15;                      // 16B align
    unsigned short* wf1 = (unsigned short*)((char*)d_ws + woff);  // [32768]
    unsigned short* wf2 = wf1 + 32768;                            // [32768]

    const int eblocks = (n_edges + 255) / 256;
    const int gather_blocks = (n_nodes + 3) / 4;
    const int gemm_blocks   = (n_nodes + 63) / 64;
    const int sort_blocks   = (n_nodes + 127) / 128;

    // ---- CSR build + W conversion (shared by both layers) ----
    hipMemsetAsync(hist, 0, (size_t)n_nodes * sizeof(int), stream);
    hist_kernel<<<eblocks, 256, 0, stream>>>(edst, hist, n_edges);
    wconv_kernel<<<32, 256, 0, stream>>>(W1, W2, wf1, wf2);
    scan_kernel<<<1, 1024, 0, stream>>>(hist, row_start, cursor, n_nodes);
    fill_kernel<<<eblocks, 256, 0, stream>>>(esrc, edst, cursor, adj, n_edges);
    sort_rows<<<sort_blocks, 128, 0, stream>>>(adj, row_start, n_nodes);

    // ---- layer 1: h -> h1 ----
    gather_kernel<<<gather_blocks, 256, 0, stream>>>(h, adj, row_start, msg, n_nodes);
    gemm_mfma<<<gemm_blocks, 256, 0, stream>>>(h, msg, wf1, b1, h1, n_nodes);

    // ---- layer 2: h1 -> out ----
    gather_kernel<<<gather_blocks, 256, 0, stream>>>(h1, adj, row_start, msg, n_nodes);
    gemm_mfma<<<gemm_blocks, 256, 0, stream>>>(h1, msg, wf2, b2, out, n_nodes);
}

// Round 7
// 257.669 us; speedup vs baseline: 1.8066x; 1.3222x over previous
//
#include <hip/hip_runtime.h>

#define D 128

typedef short short8 __attribute__((ext_vector_type(8)));
typedef float f32x4  __attribute__((ext_vector_type(4)));

__device__ __forceinline__ unsigned short f2bf(float f) {
    unsigned int u = __builtin_bit_cast(unsigned int, f);
    u += 0x7FFFu + ((u >> 16) & 1u);           // round-to-nearest-even
    return (unsigned short)(u >> 16);
}
__device__ __forceinline__ float bflo(unsigned int u) {   // bf16 in low 16 bits
    return __builtin_bit_cast(float, u << 16);
}
__device__ __forceinline__ float bfhi(unsigned int u) {   // bf16 in high 16 bits
    return __builtin_bit_cast(float, u & 0xFFFF0000u);
}

// ---------------- h (f32) -> hbf (bf16) ----------------
__global__ __launch_bounds__(256) void hconv_kernel(
    const float* __restrict__ h, unsigned short* __restrict__ hbf, int n8)
{
    const int t = blockIdx.x * 256 + threadIdx.x;
    if (t >= n8) return;
    const float4 a = reinterpret_cast<const float4*>(h)[t * 2];
    const float4 b = reinterpret_cast<const float4*>(h)[t * 2 + 1];
    union { short8 s; unsigned short u[8]; } pk;
    pk.u[0]=f2bf(a.x); pk.u[1]=f2bf(a.y); pk.u[2]=f2bf(a.z); pk.u[3]=f2bf(a.w);
    pk.u[4]=f2bf(b.x); pk.u[5]=f2bf(b.y); pk.u[6]=f2bf(b.z); pk.u[7]=f2bf(b.w);
    reinterpret_cast<short8*>(hbf)[t] = pk.s;
}

// ---------------- CSR build: histogram ----------------
__global__ __launch_bounds__(256) void hist_kernel(
    const int* __restrict__ dst, int* __restrict__ hist, int n_edges)
{
    int i = blockIdx.x * 256 + threadIdx.x;
    if (i < n_edges) atomicAdd(&hist[dst[i]], 1);
}

// ---------------- CSR build: exclusive scan (single block, 1024 thr) -------
__global__ __launch_bounds__(1024) void scan_kernel(
    const int* __restrict__ hist, int* __restrict__ row_start,
    int* __restrict__ cursor, int n)
{
    __shared__ int wsum[16];
    const int tid = threadIdx.x, lane = tid & 63, w = tid >> 6;
    int running = 0;
    const int nchunk = (n + 4095) >> 12;
    for (int c = 0; c < nchunk; ++c) {
        const int base = c * 4096 + tid * 4;
        int v0 = (base + 0 < n) ? hist[base + 0] : 0;
        int v1 = (base + 1 < n) ? hist[base + 1] : 0;
        int v2 = (base + 2 < n) ? hist[base + 2] : 0;
        int v3 = (base + 3 < n) ? hist[base + 3] : 0;
        const int s1 = v0 + v1, s2 = s1 + v2, s3 = s2 + v3;
        int incl = s3;
        #pragma unroll
        for (int off = 1; off < 64; off <<= 1) {
            int t = __shfl_up(incl, off, 64);
            if (lane >= off) incl += t;
        }
        if (lane == 63) wsum[w] = incl;
        __syncthreads();
        int wp = 0, ct = 0;
        #pragma unroll
        for (int k = 0; k < 16; ++k) { int s = wsum[k]; if (k < w) wp += s; ct += s; }
        const int ex = running + wp + incl - s3;
        if (base + 0 < n) { row_start[base + 0] = ex;      cursor[base + 0] = ex; }
        if (base + 1 < n) { row_start[base + 1] = ex + v0; cursor[base + 1] = ex + v0; }
        if (base + 2 < n) { row_start[base + 2] = ex + s1; cursor[base + 2] = ex + s1; }
        if (base + 3 < n) { row_start[base + 3] = ex + s2; cursor[base + 3] = ex + s2; }
        running += ct;
        __syncthreads();
    }
    if (tid == 0) row_start[n] = running;
}

// ---------------- CSR build: bucket fill ----------------
__global__ __launch_bounds__(256) void fill_kernel(
    const int* __restrict__ src, const int* __restrict__ dst,
    int* __restrict__ cursor, int* __restrict__ adj, int n_edges)
{
    int i = blockIdx.x * 256 + threadIdx.x;
    if (i < n_edges) {
        const int d = dst[i];
        const int pos = atomicAdd(&cursor[d], 1);
        adj[pos] = src[i];
    }
}

// ------- per-row sort (ascending src), wave-per-row bitonic via shfl -------
// Locality: all gather waves then sweep src 0->N in lockstep -> small L2 window.
__global__ __launch_bounds__(256) void sort_rows(
    int* __restrict__ adj, const int* __restrict__ row_start, int n_nodes)
{
    const int lane = threadIdx.x & 63;
    const int row  = (blockIdx.x * 256 + threadIdx.x) >> 6;
    if (row >= n_nodes) return;
    const int s0 = row_start[row], s1 = row_start[row + 1];
    const int d = s1 - s0;
    if (d <= 1 || d > 64) return;      // long rows left unsorted (perf-only)
    int v = (lane < d) ? adj[s0 + lane] : 0x7FFFFFFF;
    #pragma unroll
    for (int k = 2; k <= 64; k <<= 1) {
        #pragma unroll
        for (int j = k >> 1; j >= 1; j >>= 1) {
            const int p = __shfl_xor(v, j, 64);
            const bool keepMin = (((lane & k) == 0) == ((lane & j) == 0));
            v = keepMin ? (v < p ? v : p) : (v > p ? v : p);
        }
    }
    if (lane < d) adj[s0 + lane] = v;
}

// ------- gather (bf16): one wave per dst node; 256B rows, u32(2x bf16)/lane
__global__ __launch_bounds__(256) void gather_kernel(
    const unsigned short* __restrict__ hbf, const int* __restrict__ adj,
    const int* __restrict__ row_start, unsigned short* __restrict__ msgbf,
    int n_nodes)
{
    const int lane = threadIdx.x & 63;
    const int node = (blockIdx.x * 256 + threadIdx.x) >> 6;
    if (node >= n_nodes) return;
    const unsigned int* h2 = reinterpret_cast<const unsigned int*>(hbf);

    const int s0 = row_start[node], s1 = row_start[node + 1];
    float ax0 = 0.f, ay0 = 0.f, ax1 = 0.f, ay1 = 0.f;
    float ax2 = 0.f, ay2 = 0.f, ax3 = 0.f, ay3 = 0.f;
    int p = s0;
    for (; p + 3 < s1; p += 4) {           // 4 independent 256B row loads
        const int ia = adj[p], ib = adj[p + 1], ic = adj[p + 2], id = adj[p + 3];
        const unsigned int a = h2[(size_t)ia * 64 + lane];
        const unsigned int b = h2[(size_t)ib * 64 + lane];
        const unsigned int c = h2[(size_t)ic * 64 + lane];
        const unsigned int e = h2[(size_t)id * 64 + lane];
        ax0 += bflo(a); ay0 += bfhi(a); ax1 += bflo(b); ay1 += bfhi(b);
        ax2 += bflo(c); ay2 += bfhi(c); ax3 += bflo(e); ay3 += bfhi(e);
    }
    for (; p < s1; ++p) {
        const unsigned int a = h2[(size_t)adj[p] * 64 + lane];
        ax0 += bflo(a); ay0 += bfhi(a);
    }
    const int dg = s1 - s0;
    const float inv = 1.0f / (float)(dg > 0 ? dg : 1);
    const float sx = ((ax0 + ax1) + (ax2 + ax3)) * inv;
    const float sy = ((ay0 + ay1) + (ay2 + ay3)) * inv;
    const unsigned int o = (unsigned int)f2bf(sx) | ((unsigned int)f2bf(sy) << 16);
    reinterpret_cast<unsigned int*>(msgbf)[(size_t)node * 64 + lane] = o;
}

// ------- W -> fragment-major bf16 for mfma_f32_16x16x32_bf16 ---------------
__global__ __launch_bounds__(256) void wconv_kernel(
    const float* __restrict__ W1, const float* __restrict__ W2,
    unsigned short* __restrict__ wf1, unsigned short* __restrict__ wf2)
{
    const int t = blockIdx.x * 256 + threadIdx.x;   // 0..8191
    const int which = t >> 12;
    const int u = t & 4095;
    const float* W = which ? W2 : W1;
    unsigned short* wf = which ? wf2 : wf1;
    const int lane = u & 63;
    const int frag = u >> 6;                        // ct*8 + kc
    const int ctb  = frag >> 3;
    const int kc   = frag & 7;
    const int col  = ctb * 16 + (lane & 15);
    const int k0   = kc * 32 + (lane >> 4) * 8;
    unsigned short o[8];
    #pragma unroll
    for (int j = 0; j < 8; ++j) o[j] = f2bf(W[(size_t)(k0 + j) * D + col]);
    #pragma unroll
    for (int j = 0; j < 8; ++j) wf[(size_t)u * 8 + j] = o[j];
}

// -------- MFMA gemm: out = relu([hbf,msgbf] @ Wfrag + b) -------------------
// 256 thr = 4 waves, 64 nodes/block; wave: 16 nodes x 128 cols; K=256.
template<bool OUT_BF16>
__global__ __launch_bounds__(256) void gemm_mfma(
    const unsigned short* __restrict__ hbf, const unsigned short* __restrict__ msgbf,
    const unsigned short* __restrict__ wfrag, const float* __restrict__ bias,
    float* __restrict__ outf, unsigned short* __restrict__ outbf, int n_nodes)
{
    __shared__ unsigned short sA[64 * 256];   // 32 KB
    const int tid  = threadIdx.x;
    const int base = blockIdx.x * 64;

    // ---- stage [hbf | msgbf] rows, 16B chunks, swizzle cc ^= (r&7) ----
    #pragma unroll
    for (int it = 0; it < 8; ++it) {
        const int f  = it * 256 + tid;        // chunk id 0..2047
        const int r  = f >> 5;                // row 0..63
        const int cc = f & 31;                // 16B chunk (8 bf16)
        const int node = base + r;
        short8 v = {0,0,0,0,0,0,0,0};
        if (node < n_nodes) {
            const unsigned short* sp = (cc < 16)
                ? hbf   + (size_t)node * D + cc * 8
                : msgbf + (size_t)node * D + (cc - 16) * 8;
            v = *reinterpret_cast<const short8*>(sp);
        }
        *reinterpret_cast<short8*>(&sA[r * 256 + ((cc ^ (r & 7)) * 8)]) = v;
    }
    __syncthreads();

    const int wv   = tid >> 6;
    const int lane = tid & 63;
    const int lrow = wv * 16 + (lane & 15);
    const int lgrp = lane >> 4;

    short8 a[8];
    #pragma unroll
    for (int kc = 0; kc < 8; ++kc) {
        const int chunk = kc * 4 + lgrp;
        a[kc] = *reinterpret_cast<const short8*>(
            &sA[lrow * 256 + ((chunk ^ (lrow & 7)) * 8)]);
    }

    const short8* wf = reinterpret_cast<const short8*>(wfrag);
    f32x4 acc[8];
    #pragma unroll
    for (int ct = 0; ct < 8; ++ct) {
        const float bb = bias[ct * 16 + (lane & 15)];
        acc[ct] = (f32x4){bb, bb, bb, bb};
    }
    #pragma unroll
    for (int ct = 0; ct < 8; ++ct) {
        #pragma unroll
        for (int kc = 0; kc < 8; ++kc) {
            const short8 b = wf[(ct * 8 + kc) * 64 + lane];
            acc[ct] = __builtin_amdgcn_mfma_f32_16x16x32_bf16(a[kc], b, acc[ct], 0, 0, 0);
        }
    }

    #pragma unroll
    for (int ct = 0; ct < 8; ++ct) {
        const int col = ct * 16 + (lane & 15);
        #pragma unroll
        for (int rg = 0; rg < 4; ++rg) {
            const int node = base + wv * 16 + lgrp * 4 + rg;
            if (node < n_nodes) {
                const float r = fmaxf(acc[ct][rg], 0.f);
                if (OUT_BF16) outbf[(size_t)node * D + col] = f2bf(r);
                else          outf [(size_t)node * D + col] = r;
            }
        }
    }
}

// ---------------------------------------------------------------------------
extern "C" void kernel_launch(void* const* d_in, const int* in_sizes, int n_in,
                              void* d_out, int out_size, void* d_ws, size_t ws_size,
                              hipStream_t stream)
{
    const float* h    = (const float*)d_in[0];
    const int*   esrc = (const int*)  d_in[1];
    const int*   edst = (const int*)  d_in[2];
    const float* W1   = (const float*)d_in[3];
    const float* b1   = (const float*)d_in[4];
    const float* W2   = (const float*)d_in[5];
    const float* b2   = (const float*)d_in[6];
    float* out = (float*)d_out;

    const int n_nodes = in_sizes[0] / D;
    const int n_edges = in_sizes[1];

    // workspace layout (16B-aligned segments)
    unsigned short* hbf   = (unsigned short*)d_ws;                 // [N][D]
    unsigned short* h1bf  = hbf  + (size_t)n_nodes * D;            // [N][D]
    unsigned short* msgbf = h1bf + (size_t)n_nodes * D;            // [N][D]
    unsigned short* wf1   = msgbf + (size_t)n_nodes * D;           // [32768]
    unsigned short* wf2   = wf1 + 32768;                           // [32768]
    int* adj       = (int*)(wf2 + 32768);                          // [E]
    int* hist      = adj + n_edges;                                // [N]
    int* row_start = hist + n_nodes;                               // [N+1]
    int* cursor    = row_start + n_nodes + 1;                      // [N]

    const int eblocks = (n_edges + 255) / 256;
    const int nodewave_blocks = (n_nodes + 3) / 4;     // 1 wave per node
    const int gemm_blocks = (n_nodes + 63) / 64;
    const int hconv_blocks = ((n_nodes * D / 8) + 255) / 256;

    // ---- precompute: bf16 copies + CSR (shared by both layers) ----
    hipMemsetAsync(hist, 0, (size_t)n_nodes * sizeof(int), stream);
    hconv_kernel<<<hconv_blocks, 256, 0, stream>>>(h, hbf, n_nodes * D / 8);
    wconv_kernel<<<32, 256, 0, stream>>>(W1, W2, wf1, wf2);
    hist_kernel<<<eblocks, 256, 0, stream>>>(edst, hist, n_edges);
    scan_kernel<<<1, 1024, 0, stream>>>(hist, row_start, cursor, n_nodes);
    fill_kernel<<<eblocks, 256, 0, stream>>>(esrc, edst, cursor, adj, n_edges);
    sort_rows<<<nodewave_blocks, 256, 0, stream>>>(adj, row_start, n_nodes);

    // ---- layer 1: hbf -> h1bf ----
    gather_kernel<<<nodewave_blocks, 256, 0, stream>>>(hbf, adj, row_start, msgbf, n_nodes);
    gemm_mfma<true><<<gemm_blocks, 256, 0, stream>>>(hbf, msgbf, wf1, b1, nullptr, h1bf, n_nodes);

    // ---- layer 2: h1bf -> out (f32) ----
    gather_kernel<<<nodewave_blocks, 256, 0, stream>>>(h1bf, adj, row_start, msgbf, n_nodes);
    gemm_mfma<false><<<gemm_blocks, 256, 0, stream>>>(h1bf, msgbf, wf2, b2, out, nullptr, n_nodes);
}